// Round 18
// baseline (198.803 us; speedup 1.0000x reference)
//
#include <hip/hip_runtime.h>
#include <hip/hip_fp16.h>

#define NF   16
#define NLM  25      // (L_OUT+1)^2
#define BPB  16      // bonds per block
#define YSTR 816     // halves per bond in LDS: 800 + 16 pad

typedef _Float16 h2f __attribute__((ext_vector_type(2)));

#if defined(__has_builtin)
#if __has_builtin(__builtin_amdgcn_fdot2)
#define FDOT2(a,b,c) __builtin_amdgcn_fdot2((a),(b),(c),false)
#endif
#endif
#ifndef FDOT2
#define FDOT2(a,b,c) ((c) + (float)(a)[0]*(float)(b)[0] + (float)(a)[1]*(float)(b)[1])
#endif

#define WAVE_LDS_FENCE() asm volatile("" ::: "memory")
#define NT_STORE(p, v) __builtin_nontemporal_store((v), (p))

// ======================= compile-time real Clebsch-Gordan =======================
constexpr double FT[12] = {1.,1.,2.,6.,24.,120.,720.,5040.,40320.,362880.,3628800.,39916800.};

constexpr double csqrt(double x){
    if (x <= 0.0) return 0.0;
    double g = x > 1.0 ? x : 1.0;
    for (int i = 0; i < 60; ++i){ double n = 0.5*(g + x/g); if (n == g) break; g = n; }
    return g;
}

constexpr double cgc(int j1,int m1,int j2,int m2,int j3,int m3){
    if (m1 + m2 != m3) return 0.0;
    int dj = j1 > j2 ? j1 - j2 : j2 - j1;
    if (j3 < dj || j3 > j1 + j2) return 0.0;
    if (m1 < -j1 || m1 > j1 || m2 < -j2 || m2 > j2 || m3 < -j3 || m3 > j3) return 0.0;
    double X = (2*j3+1)*FT[j1+j2-j3]*FT[j1-j2+j3]*FT[-j1+j2+j3]/FT[j1+j2+j3+1];
    double Y = FT[j1+m1]*FT[j1-m1]*FT[j2+m2]*FT[j2-m2]*FT[j3+m3]*FT[j3-m3];
    double pre = csqrt(X*Y);
    double s = 0.0;
    int kmin = 0; if (j2-j3-m1 > kmin) kmin = j2-j3-m1; if (j1-j3+m2 > kmin) kmin = j1-j3+m2;
    int kmax = j1+j2-j3; if (j1-m1 < kmax) kmax = j1-m1; if (j2+m2 < kmax) kmax = j2+m2;
    for (int k = kmin; k <= kmax; ++k)
        s += ((k & 1) ? -1.0 : 1.0) /
             (FT[k]*FT[j1+j2-j3-k]*FT[j1-m1-k]*FT[j2+m2-k]*FT[j3-j2+m1+k]*FT[j3-j1-m2+k]);
    return pre*s;
}

struct cplx { double re, im; };

constexpr cplx Uent(int l, int a, int col){
    int mp = a - l, mm = col - l;
    const double s2 = 0.70710678118654752440;
    if (mp == 0) return (mm == 0) ? cplx{1.0,0.0} : cplx{0.0,0.0};
    if (mp > 0){
        double sgn = (mp & 1) ? -1.0 : 1.0;
        if (mm ==  mp) return cplx{sgn*s2, 0.0};
        if (mm == -mp) return cplx{s2, 0.0};
        return cplx{0.0,0.0};
    }
    int q = -mp; double sgn = (q & 1) ? -1.0 : 1.0;
    if (mm ==  q) return cplx{0.0, -sgn*s2};
    if (mm == -q) return cplx{0.0,  s2};
    return cplx{0.0,0.0};
}

constexpr double realcg(int l1,int l2,int l3,int a,int b,int c){
    double re = 0.0, im = 0.0;
    for (int m = -l1; m <= l1; ++m){
        cplx u1 = Uent(l1, a, l1+m); u1.im = -u1.im;          // conj
        if (u1.re == 0.0 && u1.im == 0.0) continue;
        for (int n = -l2; n <= l2; ++n){
            cplx u2 = Uent(l2, b, l2+n); u2.im = -u2.im;      // conj
            if (u2.re == 0.0 && u2.im == 0.0) continue;
            int k = m + n; if (k < -l3 || k > l3) continue;
            cplx u3 = Uent(l3, c, l3+k);
            if (u3.re == 0.0 && u3.im == 0.0) continue;
            double g = cgc(l1, m, l2, n, l3, k);
            if (g == 0.0) continue;
            double pr = u1.re*u2.re - u1.im*u2.im;
            double pi = u1.re*u2.im + u1.im*u2.re;
            re += (pr*u3.re - pi*u3.im)*g;
            im += (pr*u3.im + pi*u3.re)*g;
        }
    }
    double o = re + im;
    if (o < 1e-12 && o > -1e-12) o = 0.0;
    return o;
}

template<int L1,int L2,int L3> struct CGT { float v[2*L1+1][2*L2+1][2*L3+1]; };

template<int L1,int L2,int L3>
constexpr CGT<L1,L2,L3> makeCG(){
    CGT<L1,L2,L3> t{};
    for (int a = 0; a < 2*L1+1; ++a)
        for (int b = 0; b < 2*L2+1; ++b)
            for (int c = 0; c < 2*L3+1; ++c)
                t.v[a][b][c] = (float)realcg(L1, L2, L3, a, b, c);
    return t;
}

// ======================= tensor-product path (fully unrolled, sparse) =======================
template<int L1,int L2,int L3,int PIDX>
__device__ __forceinline__ void tp_path(const float (&bed)[9], const float (&y)[2][NLM],
                                        float (&o)[2][NLM], const float* __restrict__ Wtp, int g){
    static constexpr CGT<L1,L2,L3> C = makeCG<L1,L2,L3>();
    constexpr int K = 2*L3+1;
    float a0[K], a1[K];
    #pragma unroll
    for (int k = 0; k < K; ++k){ a0[k] = 0.f; a1[k] = 0.f; }
    #pragma unroll
    for (int n = 0; n < 2*L1+1; ++n){
        const float bn = bed[L1*L1 + n];
        #pragma unroll
        for (int m = 0; m < 2*L2+1; ++m){
            const float p0 = bn * y[0][L2*L2 + m];
            const float p1 = bn * y[1][L2*L2 + m];
            #pragma unroll
            for (int k = 0; k < K; ++k){
                const float c = C.v[n][m][k];
                if (c != 0.f){
                    a0[k] = fmaf(c, p0, a0[k]);
                    a1[k] = fmaf(c, p1, a1[k]);
                }
            }
        }
    }
    const float w0 = Wtp[(PIDX*2 + 0)*NF + g];
    const float w1 = Wtp[(PIDX*2 + 1)*NF + g];
    #pragma unroll
    for (int k = 0; k < K; ++k){
        if (L1 & 1){
            o[0][L3*L3 + k] = fmaf(w1, a1[k], o[0][L3*L3 + k]);
            o[1][L3*L3 + k] = fmaf(w0, a0[k], o[1][L3*L3 + k]);
        } else {
            o[0][L3*L3 + k] = fmaf(w0, a0[k], o[0][L3*L3 + k]);
            o[1][L3*L3 + k] = fmaf(w1, a1[k], o[1][L3*L3 + k]);
        }
    }
}

// ======================= weight transpose setup kernel =======================
__global__ void transpose_w(const float* __restrict__ W1, const float* __restrict__ W2,
                            const float* __restrict__ Wb, void* __restrict__ wsv){
    __half* h1 = (__half*)wsv;
    __half* h2 = h1 + 2560;
    float*  wb = (float*)(h1 + 5120);
    int idx = blockIdx.x*256 + threadIdx.x;
    if (idx < 2560){
        int mat = idx >> 8, r = (idx >> 4) & 15, c = idx & 15;
        h1[idx] = __float2half_rn(W1[mat*256 + c*16 + r]);
        h2[idx] = __float2half_rn(W2[mat*256 + c*16 + r]);
    } else if (idx < 3328){
        int k = idx - 2560; int mat = k >> 8, r = (k >> 4) & 15, c = k & 15;
        wb[k] = Wb[mat*256 + c*16 + r];
    }
}

struct H8 { float4 a, b; };   // 8 half2 = 32 B

// ================== shared device helpers (MLP part, used by both paths) ==================
__device__ __forceinline__ void mlp_body(const float* __restrict__ A, const int* __restrict__ nbr,
                                         const float* __restrict__ b1, const float* __restrict__ gamma,
                                         const float* __restrict__ beta, const float* __restrict__ b2,
                                         const __half* __restrict__ Wt1h, const __half* __restrict__ Wt2h,
                                         __half* yb, int bond, int g, bool act, float (&y)[2][NLM]){
    if (act){
        const int i = nbr[2*bond], j = nbr[2*bond+1];
        const float4* Ai = (const float4*)(A + (size_t)i*800);
        const float4* Aj = (const float4*)(A + (size_t)j*800);
        #pragma unroll
        for (int it = 0; it < 13; ++it){
            int q = g + 16*it;
            if (q < 200){
                float4 a = Ai[q], b = Aj[q];
                __half2* d = (__half2*)&yb[4*q];
                d[0] = __float22half2_rn(make_float2(a.x+b.x, a.y+b.y));
                d[1] = __float22half2_rn(make_float2(a.z+b.z, a.w+b.w));
            }
        }
    }
    WAVE_LDS_FENCE();

    if (act){
        #pragma unroll
        for (int p = 0; p < 2; ++p){
            #pragma unroll
            for (int l = 0; l < 5; ++l){
                H8 wv = *(const H8*)(Wt1h + (((p*5 + l)*16 + g) << 4));
                const h2f* w = (const h2f*)&wv;
                #pragma unroll
                for (int m = 0; m < 2*l+1; ++m){
                    const int lm = l*l + m;
                    H8 rv = *(const H8*)&yb[p*400 + lm*16];
                    const h2f* v = (const h2f*)&rv;
                    float acc = 0.f;
                    #pragma unroll
                    for (int q = 0; q < 8; ++q) acc = FDOT2(v[q], w[q], acc);
                    y[p][lm] = acc;
                }
            }
        }
        y[0][0] += b1[g];

        float s0 = y[0][0];
        #pragma unroll
        for (int p = 0; p < 2; ++p){
            #pragma unroll
            for (int l = 0; l < 5; ++l){
                float n2 = 0.f;
                #pragma unroll
                for (int m = 0; m < 2*l+1; ++m){ float v = y[p][l*l+m]; n2 = fmaf(v, v, n2); }
                #pragma unroll
                for (int d = 1; d < 16; d <<= 1) n2 += __shfl_xor(n2, d, 16);
                float rinv = rsqrtf(n2*(1.f/16.f) + 1e-5f);
                float sc = rinv * gamma[(p*5 + l)*16 + g];
                #pragma unroll
                for (int m = 0; m < 2*l+1; ++m) y[p][l*l+m] *= sc;
            }
        }
        float mu = s0, sq = s0*s0;
        #pragma unroll
        for (int d = 1; d < 16; d <<= 1){ mu += __shfl_xor(mu, d, 16); sq += __shfl_xor(sq, d, 16); }
        mu *= (1.f/16.f); sq *= (1.f/16.f);
        float var = sq - mu*mu;
        float sh = (s0 - mu)*rsqrtf(var + 1e-5f)*gamma[g] + beta[g];
        y[0][0] = sh;

        float s  = sh;
        float es = __expf(fminf(s, 30.f));
        float es2 = es*es;
        float t   = (es2 + 2.f*es) / (es2 + 2.f*es + 2.f);
        float sig = es / (1.f + es);
        float fv  = s*t;
        float fp  = t + s*(1.f - t*t)*sig;
        #pragma unroll
        for (int p = 0; p < 2; ++p)
            #pragma unroll
            for (int lm = 0; lm < NLM; ++lm) y[p][lm] *= fp;
        y[0][0] = fv;
    }
    WAVE_LDS_FENCE();

    if (act){
        #pragma unroll
        for (int p = 0; p < 2; ++p)
            #pragma unroll
            for (int lm = 0; lm < NLM; ++lm)
                yb[p*400 + lm*16 + g] = __float2half_rn(y[p][lm]);
    }
    WAVE_LDS_FENCE();

    if (act){
        #pragma unroll
        for (int p = 0; p < 2; ++p){
            #pragma unroll
            for (int l = 0; l < 5; ++l){
                H8 wv = *(const H8*)(Wt2h + (((p*5 + l)*16 + g) << 4));
                const h2f* w = (const h2f*)&wv;
                #pragma unroll
                for (int m = 0; m < 2*l+1; ++m){
                    const int lm = l*l + m;
                    H8 rv = *(const H8*)&yb[p*400 + lm*16];
                    const h2f* v = (const h2f*)&rv;
                    float acc = 0.f;
                    #pragma unroll
                    for (int q = 0; q < 8; ++q) acc = FDOT2(v[q], w[q], acc);
                    y[p][lm] += acc;
                }
            }
        }
        y[0][0] += b2[g];
    }
}

__device__ __forceinline__ void tp_body(const float* __restrict__ disp, const float* __restrict__ bb,
                                        const float* __restrict__ Wtp, const float* __restrict__ Wtb,
                                        float* __restrict__ out, int bond, int g,
                                        const float (&y)[2][NLM]){
    float dx = disp[3*bond], dy = disp[3*bond+1], dz = disp[3*bond+2];
    float r  = sqrtf(dx*dx + dy*dy + dz*dz);
    float ir = 1.f/(r + 1e-12f);
    float ux = dx*ir, uy = dy*ir, uz = dz*ir;
    float Y[9];
    Y[0] = 0.28209479177387814f;
    Y[1] = 0.4886025119029199f*uy; Y[2] = 0.4886025119029199f*uz; Y[3] = 0.4886025119029199f*ux;
    Y[4] = 1.0925484305920792f*ux*uy; Y[5] = 1.0925484305920792f*uy*uz;
    Y[6] = 0.31539156525252005f*(3.f*uz*uz - 1.f);
    Y[7] = 1.0925484305920792f*ux*uz; Y[8] = 0.5462742152960396f*(ux*ux - uy*uy);
    float cut = (r < 5.0f) ? 0.5f*(__cosf(r*0.62831853071795864769f) + 1.f) : 0.f;
    float rb[16];
    #pragma unroll
    for (int f = 0; f < 16; ++f){
        float d = (r - (float)f*(1.f/3.f))*3.2f;
        rb[f] = __expf(-d*d)*cut;
    }
    float t3[3];
    #pragma unroll
    for (int l = 0; l < 3; ++l){
        const float4* wp = (const float4*)(Wtb + (l*16 + g)*16);
        float acc = 0.f;
        #pragma unroll
        for (int q = 0; q < 4; ++q){
            float4 t = wp[q];
            acc = fmaf(rb[4*q],   t.x, acc);
            acc = fmaf(rb[4*q+1], t.y, acc);
            acc = fmaf(rb[4*q+2], t.z, acc);
            acc = fmaf(rb[4*q+3], t.w, acc);
        }
        t3[l] = acc;
    }
    float bed[9];
    bed[0] = Y[0]*t3[0] + bb[g];
    #pragma unroll
    for (int m = 1; m < 4; ++m) bed[m] = Y[m]*t3[1];
    #pragma unroll
    for (int m = 4; m < 9; ++m) bed[m] = Y[m]*t3[2];

    float o[2][NLM];
    #pragma unroll
    for (int p = 0; p < 2; ++p)
        #pragma unroll
        for (int lm = 0; lm < NLM; ++lm) o[p][lm] = 0.f;

    tp_path<0,0,0, 0>(bed, y, o, Wtp, g);
    tp_path<0,1,1, 1>(bed, y, o, Wtp, g);
    tp_path<0,2,2, 2>(bed, y, o, Wtp, g);
    tp_path<0,3,3, 3>(bed, y, o, Wtp, g);
    tp_path<0,4,4, 4>(bed, y, o, Wtp, g);
    tp_path<1,0,1, 5>(bed, y, o, Wtp, g);
    tp_path<1,1,0, 6>(bed, y, o, Wtp, g);
    tp_path<1,1,1, 7>(bed, y, o, Wtp, g);
    tp_path<1,1,2, 8>(bed, y, o, Wtp, g);
    tp_path<1,2,1, 9>(bed, y, o, Wtp, g);
    tp_path<1,2,2,10>(bed, y, o, Wtp, g);
    tp_path<1,2,3,11>(bed, y, o, Wtp, g);
    tp_path<1,3,2,12>(bed, y, o, Wtp, g);
    tp_path<1,3,3,13>(bed, y, o, Wtp, g);
    tp_path<1,3,4,14>(bed, y, o, Wtp, g);
    tp_path<1,4,3,15>(bed, y, o, Wtp, g);
    tp_path<1,4,4,16>(bed, y, o, Wtp, g);
    tp_path<2,0,2,17>(bed, y, o, Wtp, g);
    tp_path<2,1,1,18>(bed, y, o, Wtp, g);
    tp_path<2,1,2,19>(bed, y, o, Wtp, g);
    tp_path<2,1,3,20>(bed, y, o, Wtp, g);
    tp_path<2,2,0,21>(bed, y, o, Wtp, g);
    tp_path<2,2,1,22>(bed, y, o, Wtp, g);
    tp_path<2,2,2,23>(bed, y, o, Wtp, g);
    tp_path<2,2,3,24>(bed, y, o, Wtp, g);
    tp_path<2,2,4,25>(bed, y, o, Wtp, g);
    tp_path<2,3,1,26>(bed, y, o, Wtp, g);
    tp_path<2,3,2,27>(bed, y, o, Wtp, g);
    tp_path<2,3,3,28>(bed, y, o, Wtp, g);
    tp_path<2,3,4,29>(bed, y, o, Wtp, g);
    tp_path<2,4,2,30>(bed, y, o, Wtp, g);
    tp_path<2,4,3,31>(bed, y, o, Wtp, g);
    tp_path<2,4,4,32>(bed, y, o, Wtp, g);

    float* op = out + (size_t)bond*800;
    #pragma unroll
    for (int p = 0; p < 2; ++p)
        #pragma unroll
        for (int lm = 0; lm < NLM; ++lm)
            NT_STORE(&op[p*400 + lm*16 + g], o[p][lm]);
}

// ======================= SPLIT kernel A: gather + MLP -> y (f16) =======================
// Live set ~80 floats -> fits the 128-unified class -> (256,4) = 16 waves/CU
// for the gather-latency-bound portion (vs 12 in the monolith).
__global__ __launch_bounds__(256, 4)
void bctmd_front(const float* __restrict__ A, const int* __restrict__ nbr,
                 const float* __restrict__ b1, const float* __restrict__ gamma,
                 const float* __restrict__ beta, const float* __restrict__ b2,
                 const __half* __restrict__ Wt1h, const __half* __restrict__ Wt2h,
                 __half* __restrict__ yws, int nb)
{
    __shared__ __align__(16) __half ybuf[BPB*YSTR];
    const int tid  = threadIdx.x;
    const int bl   = tid >> 4;
    const int g    = tid & 15;
    const int bond = blockIdx.x*BPB + bl;
    const bool act = bond < nb;
    __half* yb = &ybuf[bl*YSTR];

    float y[2][NLM];
    mlp_body(A, nbr, b1, gamma, beta, b2, Wt1h, Wt2h, yb, bond, g, act, y);

    if (act){
        __half* yo = yws + (size_t)bond*800;
        #pragma unroll
        for (int p = 0; p < 2; ++p)
            #pragma unroll
            for (int lm = 0; lm < NLM; ++lm)
                yo[p*400 + lm*16 + g] = __float2half_rn(y[p][lm]);
    }
}

// ======================= SPLIT kernel B: y (f16) -> basis + TP -> out =======================
// No LDS, no gather: 50 streamed y loads then a pure fma storm -> high VALUBusy
// even at the 170-class (live ~115 floats, same proven shape as R11's TP).
__global__ __launch_bounds__(256, 3)
void bctmd_tp(const __half* __restrict__ yws, const float* __restrict__ disp,
              const float* __restrict__ bb, const float* __restrict__ Wtp,
              const float* __restrict__ Wtb, float* __restrict__ out, int nb)
{
    const int tid  = threadIdx.x;
    const int bl   = tid >> 4;
    const int g    = tid & 15;
    const int bond = blockIdx.x*BPB + bl;
    if (bond >= nb) return;

    float y[2][NLM];
    const __half* yi = yws + (size_t)bond*800;
    #pragma unroll
    for (int p = 0; p < 2; ++p)
        #pragma unroll
        for (int lm = 0; lm < NLM; ++lm)
            y[p][lm] = __half2float(yi[p*400 + lm*16 + g]);

    tp_body(disp, bb, Wtp, Wtb, out, bond, g, y);
}

// ======================= FALLBACK: monolithic R17 kernel (proven 186us) =======================
__global__ __launch_bounds__(256, 3)
void bctmd_kernel(const float* __restrict__ A, const int* __restrict__ nbr,
                  const float* __restrict__ disp,
                  const float* __restrict__ b1, const float* __restrict__ gamma,
                  const float* __restrict__ beta, const float* __restrict__ b2,
                  const float* __restrict__ bb, const float* __restrict__ Wtp,
                  const __half* __restrict__ Wt1h, const __half* __restrict__ Wt2h,
                  const float* __restrict__ Wtb,
                  float* __restrict__ out, int nb)
{
    __shared__ __align__(16) __half ybuf[BPB*YSTR];
    const int tid  = threadIdx.x;
    const int bl   = tid >> 4;
    const int g    = tid & 15;
    const int bond = blockIdx.x*BPB + bl;
    const bool act = bond < nb;
    __half* yb = &ybuf[bl*YSTR];

    float y[2][NLM];
    mlp_body(A, nbr, b1, gamma, beta, b2, Wt1h, Wt2h, yb, bond, g, act, y);

    if (act) tp_body(disp, bb, Wtp, Wtb, out, bond, g, y);
}

extern "C" void kernel_launch(void* const* d_in, const int* in_sizes, int n_in,
                              void* d_out, int out_size, void* d_ws, size_t ws_size,
                              hipStream_t stream){
    const float* A     = (const float*)d_in[0];
    const int*   nbr   = (const int*)d_in[1];
    const float* disp  = (const float*)d_in[2];
    const float* W1    = (const float*)d_in[3];
    const float* b1    = (const float*)d_in[4];
    const float* gamma = (const float*)d_in[5];
    const float* beta  = (const float*)d_in[6];
    const float* W2    = (const float*)d_in[7];
    const float* b2    = (const float*)d_in[8];
    const float* Wb    = (const float*)d_in[9];
    const float* bb    = (const float*)d_in[10];
    const float* Wtp   = (const float*)d_in[11];

    const int nb = in_sizes[1] / 2;

    hipLaunchKernelGGL(transpose_w, dim3(13), dim3(256), 0, stream, W1, W2, Wb, d_ws);

    const __half* h1 = (const __half*)d_ws;
    const __half* h2 = h1 + 2560;
    const float*  wb = (const float*)(h1 + 5120);

    const int nblk = (nb + BPB - 1) / BPB;
    const size_t y_off   = 16384;                       // bytes, past weight tables
    const size_t y_bytes = (size_t)nb * 800 * sizeof(__half);

    if (ws_size >= y_off + y_bytes){
        __half* yws = (__half*)((char*)d_ws + y_off);
        hipLaunchKernelGGL(bctmd_front, dim3(nblk), dim3(256), 0, stream,
                           A, nbr, b1, gamma, beta, b2, h1, h2, yws, nb);
        hipLaunchKernelGGL(bctmd_tp, dim3(nblk), dim3(256), 0, stream,
                           yws, disp, bb, Wtp, wb, (float*)d_out, nb);
    } else {
        hipLaunchKernelGGL(bctmd_kernel, dim3(nblk), dim3(256), 0, stream,
                           A, nbr, disp, b1, gamma, beta, b2, bb, Wtp,
                           h1, h2, wb, (float*)d_out, nb);
    }
}

// Round 19
// 186.046 us; speedup vs baseline: 1.0686x; 1.0686x over previous
//
#include <hip/hip_runtime.h>
#include <hip/hip_fp16.h>

#define NF   16
#define NLM  25      // (L_OUT+1)^2
#define BPB  16      // bonds per block
#define YSTR 816     // halves per bond in LDS: 800 + 16 pad; 1632 B stride

typedef _Float16 h2f __attribute__((ext_vector_type(2)));

#if defined(__has_builtin)
#if __has_builtin(__builtin_amdgcn_fdot2)
#define FDOT2(a,b,c) __builtin_amdgcn_fdot2((a),(b),(c),false)
#endif
#endif
#ifndef FDOT2
#define FDOT2(a,b,c) ((c) + (float)(a)[0]*(float)(b)[0] + (float)(a)[1]*(float)(b)[1])
#endif

// Wave-private LDS fence (R16): LDS rows are only shared within one wave,
// HW LDS is in-order per wave, so a compiler-reorder fence replaces s_barrier.
#define WAVE_LDS_FENCE() asm volatile("" ::: "memory")

// Non-temporal store for the streamed, write-once output (R17: -5us, FETCH -9MB).
#define NT_STORE(p, v) __builtin_nontemporal_store((v), (p))

// ======================= compile-time real Clebsch-Gordan =======================
constexpr double FT[12] = {1.,1.,2.,6.,24.,120.,720.,5040.,40320.,362880.,3628800.,39916800.};

constexpr double csqrt(double x){
    if (x <= 0.0) return 0.0;
    double g = x > 1.0 ? x : 1.0;
    for (int i = 0; i < 60; ++i){ double n = 0.5*(g + x/g); if (n == g) break; g = n; }
    return g;
}

constexpr double cgc(int j1,int m1,int j2,int m2,int j3,int m3){
    if (m1 + m2 != m3) return 0.0;
    int dj = j1 > j2 ? j1 - j2 : j2 - j1;
    if (j3 < dj || j3 > j1 + j2) return 0.0;
    if (m1 < -j1 || m1 > j1 || m2 < -j2 || m2 > j2 || m3 < -j3 || m3 > j3) return 0.0;
    double X = (2*j3+1)*FT[j1+j2-j3]*FT[j1-j2+j3]*FT[-j1+j2+j3]/FT[j1+j2+j3+1];
    double Y = FT[j1+m1]*FT[j1-m1]*FT[j2+m2]*FT[j2-m2]*FT[j3+m3]*FT[j3-m3];
    double pre = csqrt(X*Y);
    double s = 0.0;
    int kmin = 0; if (j2-j3-m1 > kmin) kmin = j2-j3-m1; if (j1-j3+m2 > kmin) kmin = j1-j3+m2;
    int kmax = j1+j2-j3; if (j1-m1 < kmax) kmax = j1-m1; if (j2+m2 < kmax) kmax = j2+m2;
    for (int k = kmin; k <= kmax; ++k)
        s += ((k & 1) ? -1.0 : 1.0) /
             (FT[k]*FT[j1+j2-j3-k]*FT[j1-m1-k]*FT[j2+m2-k]*FT[j3-j2+m1+k]*FT[j3-j1-m2+k]);
    return pre*s;
}

struct cplx { double re, im; };

constexpr cplx Uent(int l, int a, int col){
    int mp = a - l, mm = col - l;
    const double s2 = 0.70710678118654752440;
    if (mp == 0) return (mm == 0) ? cplx{1.0,0.0} : cplx{0.0,0.0};
    if (mp > 0){
        double sgn = (mp & 1) ? -1.0 : 1.0;
        if (mm ==  mp) return cplx{sgn*s2, 0.0};
        if (mm == -mp) return cplx{s2, 0.0};
        return cplx{0.0,0.0};
    }
    int q = -mp; double sgn = (q & 1) ? -1.0 : 1.0;
    if (mm ==  q) return cplx{0.0, -sgn*s2};
    if (mm == -q) return cplx{0.0,  s2};
    return cplx{0.0,0.0};
}

constexpr double realcg(int l1,int l2,int l3,int a,int b,int c){
    double re = 0.0, im = 0.0;
    for (int m = -l1; m <= l1; ++m){
        cplx u1 = Uent(l1, a, l1+m); u1.im = -u1.im;          // conj
        if (u1.re == 0.0 && u1.im == 0.0) continue;
        for (int n = -l2; n <= l2; ++n){
            cplx u2 = Uent(l2, b, l2+n); u2.im = -u2.im;      // conj
            if (u2.re == 0.0 && u2.im == 0.0) continue;
            int k = m + n; if (k < -l3 || k > l3) continue;
            cplx u3 = Uent(l3, c, l3+k);
            if (u3.re == 0.0 && u3.im == 0.0) continue;
            double g = cgc(l1, m, l2, n, l3, k);
            if (g == 0.0) continue;
            double pr = u1.re*u2.re - u1.im*u2.im;
            double pi = u1.re*u2.im + u1.im*u2.re;
            re += (pr*u3.re - pi*u3.im)*g;
            im += (pr*u3.im + pi*u3.re)*g;
        }
    }
    double o = re + im;
    if (o < 1e-12 && o > -1e-12) o = 0.0;
    return o;
}

template<int L1,int L2,int L3> struct CGT { float v[2*L1+1][2*L2+1][2*L3+1]; };

template<int L1,int L2,int L3>
constexpr CGT<L1,L2,L3> makeCG(){
    CGT<L1,L2,L3> t{};
    for (int a = 0; a < 2*L1+1; ++a)
        for (int b = 0; b < 2*L2+1; ++b)
            for (int c = 0; c < 2*L3+1; ++c)
                t.v[a][b][c] = (float)realcg(L1, L2, L3, a, b, c);
    return t;
}

// ======================= tensor-product path (fully unrolled, sparse) =======================
template<int L1,int L2,int L3,int PIDX>
__device__ __forceinline__ void tp_path(const float (&bed)[9], const float (&y)[2][NLM],
                                        float (&o)[2][NLM], const float* __restrict__ Wtp, int g){
    static constexpr CGT<L1,L2,L3> C = makeCG<L1,L2,L3>();
    constexpr int K = 2*L3+1;
    float a0[K], a1[K];
    #pragma unroll
    for (int k = 0; k < K; ++k){ a0[k] = 0.f; a1[k] = 0.f; }
    #pragma unroll
    for (int n = 0; n < 2*L1+1; ++n){
        const float bn = bed[L1*L1 + n];
        #pragma unroll
        for (int m = 0; m < 2*L2+1; ++m){
            const float p0 = bn * y[0][L2*L2 + m];
            const float p1 = bn * y[1][L2*L2 + m];
            #pragma unroll
            for (int k = 0; k < K; ++k){
                const float c = C.v[n][m][k];
                if (c != 0.f){        // folds at compile time -> sparse code
                    a0[k] = fmaf(c, p0, a0[k]);
                    a1[k] = fmaf(c, p1, a1[k]);
                }
            }
        }
    }
    const float w0 = Wtp[(PIDX*2 + 0)*NF + g];
    const float w1 = Wtp[(PIDX*2 + 1)*NF + g];
    #pragma unroll
    for (int k = 0; k < K; ++k){
        if (L1 & 1){   // odd l1: parity channels swap
            o[0][L3*L3 + k] = fmaf(w1, a1[k], o[0][L3*L3 + k]);
            o[1][L3*L3 + k] = fmaf(w0, a0[k], o[1][L3*L3 + k]);
        } else {
            o[0][L3*L3 + k] = fmaf(w0, a0[k], o[0][L3*L3 + k]);
            o[1][L3*L3 + k] = fmaf(w1, a1[k], o[1][L3*L3 + k]);
        }
    }
}

// ======================= weight transpose setup kernel =======================
// ws layout (bytes): Wt1h f16 @0 (5120 B), Wt2h f16 @5120 (5120 B),
//                    Wtb f32 @10240 (3072 B). Wt[mat][g][f] = W[mat][f][g].
__global__ void transpose_w(const float* __restrict__ W1, const float* __restrict__ W2,
                            const float* __restrict__ Wb, void* __restrict__ wsv){
    __half* h1 = (__half*)wsv;
    __half* h2 = h1 + 2560;
    float*  wb = (float*)(h1 + 5120);
    int idx = blockIdx.x*256 + threadIdx.x;
    if (idx < 2560){
        int mat = idx >> 8, r = (idx >> 4) & 15, c = idx & 15;
        h1[idx] = __float2half_rn(W1[mat*256 + c*16 + r]);
        h2[idx] = __float2half_rn(W2[mat*256 + c*16 + r]);
    } else if (idx < 3328){
        int k = idx - 2560; int mat = k >> 8, r = (k >> 4) & 15, c = k & 15;
        wb[k] = Wb[mat*256 + c*16 + r];
    }
}

struct H8 { float4 a, b; };   // 8 half2 = 32 B

// ======================= main fused kernel (R17, best verified: 185.7us) =======================
// f16 LDS staging (26112 B), f16 dot2 denses, wave-private fences instead of
// barriers, NT output stores. VGPR 84, spill-free, ~12 waves/CU. The session's
// constraint surface: RA pins the spill-free point at the 3-waves/EU unified-RF
// class (live ~124 floats); 7 structural escape attempts all regressed.
__global__ __launch_bounds__(256, 3)
void bctmd_kernel(const float* __restrict__ A, const int* __restrict__ nbr,
                  const float* __restrict__ disp,
                  const float* __restrict__ b1, const float* __restrict__ gamma,
                  const float* __restrict__ beta, const float* __restrict__ b2,
                  const float* __restrict__ bb, const float* __restrict__ Wtp,
                  const __half* __restrict__ Wt1h, const __half* __restrict__ Wt2h,
                  const float* __restrict__ Wtb,
                  float* __restrict__ out, int nb)
{
    __shared__ __align__(16) __half ybuf[BPB*YSTR];
    const int tid  = threadIdx.x;
    const int bl   = tid >> 4;       // bond slot in block
    const int g    = tid & 15;       // feature lane
    const int bond = blockIdx.x*BPB + bl;
    const bool act = bond < nb;
    __half* yb = &ybuf[bl*YSTR];

    // ---- stage A: y0 = A[i] + A[j] -> LDS as f16 (cooperative) ----
    if (act){
        const int i = nbr[2*bond], j = nbr[2*bond+1];
        const float4* Ai = (const float4*)(A + (size_t)i*800);
        const float4* Aj = (const float4*)(A + (size_t)j*800);
        #pragma unroll
        for (int it = 0; it < 13; ++it){
            int q = g + 16*it;
            if (q < 200){
                float4 a = Ai[q], b = Aj[q];
                __half2* d = (__half2*)&yb[4*q];
                d[0] = __float22half2_rn(make_float2(a.x+b.x, a.y+b.y));
                d[1] = __float22half2_rn(make_float2(a.z+b.z, a.w+b.w));
            }
        }
    }
    WAVE_LDS_FENCE();

    float y[2][NLM];
    if (act){
        // ---- edense1: y1[p][lm][g] = sum_f y0[p][lm][f] * W1[p,l][f][g] ----
        #pragma unroll
        for (int p = 0; p < 2; ++p){
            #pragma unroll
            for (int l = 0; l < 5; ++l){
                H8 wv = *(const H8*)(Wt1h + (((p*5 + l)*16 + g) << 4));
                const h2f* w = (const h2f*)&wv;
                #pragma unroll
                for (int m = 0; m < 2*l+1; ++m){
                    const int lm = l*l + m;
                    H8 rv = *(const H8*)&yb[p*400 + lm*16];
                    const h2f* v = (const h2f*)&rv;
                    float acc = 0.f;
                    #pragma unroll
                    for (int q = 0; q < 8; ++q) acc = FDOT2(v[q], w[q], acc);
                    y[p][lm] = acc;
                }
            }
        }
        y[0][0] += b1[g];

        // ---- eln ----
        float s0 = y[0][0];   // scalar channel BEFORE normalization
        #pragma unroll
        for (int p = 0; p < 2; ++p){
            #pragma unroll
            for (int l = 0; l < 5; ++l){
                float n2 = 0.f;
                #pragma unroll
                for (int m = 0; m < 2*l+1; ++m){ float v = y[p][l*l+m]; n2 = fmaf(v, v, n2); }
                #pragma unroll
                for (int d = 1; d < 16; d <<= 1) n2 += __shfl_xor(n2, d, 16);
                float rinv = rsqrtf(n2*(1.f/16.f) + 1e-5f);
                float sc = rinv * gamma[(p*5 + l)*16 + g];
                #pragma unroll
                for (int m = 0; m < 2*l+1; ++m) y[p][l*l+m] *= sc;
            }
        }
        // scalar LayerNorm (p=0, lm=0) on pre-norm value
        float mu = s0, sq = s0*s0;
        #pragma unroll
        for (int d = 1; d < 16; d <<= 1){ mu += __shfl_xor(mu, d, 16); sq += __shfl_xor(sq, d, 16); }
        mu *= (1.f/16.f); sq *= (1.f/16.f);
        float var = sq - mu*mu;
        float sh = (s0 - mu)*rsqrtf(var + 1e-5f)*gamma[g] + beta[g];
        y[0][0] = sh;

        // ---- emish ---- (single exp formulation)
        float s  = sh;
        float es = __expf(fminf(s, 30.f));
        float es2 = es*es;
        float t   = (es2 + 2.f*es) / (es2 + 2.f*es + 2.f);  // tanh(softplus(s))
        float sig = es / (1.f + es);
        float fv  = s*t;
        float fp  = t + s*(1.f - t*t)*sig;
        #pragma unroll
        for (int p = 0; p < 2; ++p)
            #pragma unroll
            for (int lm = 0; lm < NLM; ++lm) y[p][lm] *= fp;
        y[0][0] = fv;
    }
    WAVE_LDS_FENCE();       // all edense1 reads of ybuf done (wave-local)

    if (act){
        #pragma unroll
        for (int p = 0; p < 2; ++p)
            #pragma unroll
            for (int lm = 0; lm < NLM; ++lm)
                yb[p*400 + lm*16 + g] = __float2half_rn(y[p][lm]);
    }
    WAVE_LDS_FENCE();       // post-mish y visible to this wave's lanes

    if (act){
        // ---- edense2 + b2 + residual ----
        #pragma unroll
        for (int p = 0; p < 2; ++p){
            #pragma unroll
            for (int l = 0; l < 5; ++l){
                H8 wv = *(const H8*)(Wt2h + (((p*5 + l)*16 + g) << 4));
                const h2f* w = (const h2f*)&wv;
                #pragma unroll
                for (int m = 0; m < 2*l+1; ++m){
                    const int lm = l*l + m;
                    H8 rv = *(const H8*)&yb[p*400 + lm*16];
                    const h2f* v = (const h2f*)&rv;
                    float acc = 0.f;
                    #pragma unroll
                    for (int q = 0; q < 8; ++q) acc = FDOT2(v[q], w[q], acc);
                    y[p][lm] += acc;     // residual
                }
            }
        }
        y[0][0] += b2[g];

        // ---- basis + basis edense (rank-1 factorized) ----
        float dx = disp[3*bond], dy = disp[3*bond+1], dz = disp[3*bond+2];
        float r  = sqrtf(dx*dx + dy*dy + dz*dz);
        float ir = 1.f/(r + 1e-12f);
        float ux = dx*ir, uy = dy*ir, uz = dz*ir;
        float Y[9];
        Y[0] = 0.28209479177387814f;
        Y[1] = 0.4886025119029199f*uy; Y[2] = 0.4886025119029199f*uz; Y[3] = 0.4886025119029199f*ux;
        Y[4] = 1.0925484305920792f*ux*uy; Y[5] = 1.0925484305920792f*uy*uz;
        Y[6] = 0.31539156525252005f*(3.f*uz*uz - 1.f);
        Y[7] = 1.0925484305920792f*ux*uz; Y[8] = 0.5462742152960396f*(ux*ux - uy*uy);
        float cut = (r < 5.0f) ? 0.5f*(__cosf(r*0.62831853071795864769f) + 1.f) : 0.f;
        float rb[16];
        #pragma unroll
        for (int f = 0; f < 16; ++f){
            float d = (r - (float)f*(1.f/3.f))*3.2f;   // width = 5/16
            rb[f] = __expf(-d*d)*cut;
        }
        float t3[3];
        #pragma unroll
        for (int l = 0; l < 3; ++l){
            const float4* wp = (const float4*)(Wtb + (l*16 + g)*16);
            float acc = 0.f;
            #pragma unroll
            for (int q = 0; q < 4; ++q){
                float4 t = wp[q];
                acc = fmaf(rb[4*q],   t.x, acc);
                acc = fmaf(rb[4*q+1], t.y, acc);
                acc = fmaf(rb[4*q+2], t.z, acc);
                acc = fmaf(rb[4*q+3], t.w, acc);
            }
            t3[l] = acc;
        }
        float bed[9];
        bed[0] = Y[0]*t3[0] + bb[g];
        #pragma unroll
        for (int m = 1; m < 4; ++m) bed[m] = Y[m]*t3[1];
        #pragma unroll
        for (int m = 4; m < 9; ++m) bed[m] = Y[m]*t3[2];

        // ---- tensor product (33 paths, compile-time sparse CG) ----
        float o[2][NLM];
        #pragma unroll
        for (int p = 0; p < 2; ++p)
            #pragma unroll
            for (int lm = 0; lm < NLM; ++lm) o[p][lm] = 0.f;

        tp_path<0,0,0, 0>(bed, y, o, Wtp, g);
        tp_path<0,1,1, 1>(bed, y, o, Wtp, g);
        tp_path<0,2,2, 2>(bed, y, o, Wtp, g);
        tp_path<0,3,3, 3>(bed, y, o, Wtp, g);
        tp_path<0,4,4, 4>(bed, y, o, Wtp, g);
        tp_path<1,0,1, 5>(bed, y, o, Wtp, g);
        tp_path<1,1,0, 6>(bed, y, o, Wtp, g);
        tp_path<1,1,1, 7>(bed, y, o, Wtp, g);
        tp_path<1,1,2, 8>(bed, y, o, Wtp, g);
        tp_path<1,2,1, 9>(bed, y, o, Wtp, g);
        tp_path<1,2,2,10>(bed, y, o, Wtp, g);
        tp_path<1,2,3,11>(bed, y, o, Wtp, g);
        tp_path<1,3,2,12>(bed, y, o, Wtp, g);
        tp_path<1,3,3,13>(bed, y, o, Wtp, g);
        tp_path<1,3,4,14>(bed, y, o, Wtp, g);
        tp_path<1,4,3,15>(bed, y, o, Wtp, g);
        tp_path<1,4,4,16>(bed, y, o, Wtp, g);
        tp_path<2,0,2,17>(bed, y, o, Wtp, g);
        tp_path<2,1,1,18>(bed, y, o, Wtp, g);
        tp_path<2,1,2,19>(bed, y, o, Wtp, g);
        tp_path<2,1,3,20>(bed, y, o, Wtp, g);
        tp_path<2,2,0,21>(bed, y, o, Wtp, g);
        tp_path<2,2,1,22>(bed, y, o, Wtp, g);
        tp_path<2,2,2,23>(bed, y, o, Wtp, g);
        tp_path<2,2,3,24>(bed, y, o, Wtp, g);
        tp_path<2,2,4,25>(bed, y, o, Wtp, g);
        tp_path<2,3,1,26>(bed, y, o, Wtp, g);
        tp_path<2,3,2,27>(bed, y, o, Wtp, g);
        tp_path<2,3,3,28>(bed, y, o, Wtp, g);
        tp_path<2,3,4,29>(bed, y, o, Wtp, g);
        tp_path<2,4,2,30>(bed, y, o, Wtp, g);
        tp_path<2,4,3,31>(bed, y, o, Wtp, g);
        tp_path<2,4,4,32>(bed, y, o, Wtp, g);

        // ---- store (non-temporal: don't pollute L2/L3 against the A-gather) ----
        float* op = out + (size_t)bond*800;
        #pragma unroll
        for (int p = 0; p < 2; ++p)
            #pragma unroll
            for (int lm = 0; lm < NLM; ++lm)
                NT_STORE(&op[p*400 + lm*16 + g], o[p][lm]);
    }
}

extern "C" void kernel_launch(void* const* d_in, const int* in_sizes, int n_in,
                              void* d_out, int out_size, void* d_ws, size_t ws_size,
                              hipStream_t stream){
    const float* A     = (const float*)d_in[0];
    const int*   nbr   = (const int*)d_in[1];
    const float* disp  = (const float*)d_in[2];
    const float* W1    = (const float*)d_in[3];
    const float* b1    = (const float*)d_in[4];
    const float* gamma = (const float*)d_in[5];
    const float* beta  = (const float*)d_in[6];
    const float* W2    = (const float*)d_in[7];
    const float* b2    = (const float*)d_in[8];
    const float* Wb    = (const float*)d_in[9];
    const float* bb    = (const float*)d_in[10];
    const float* Wtp   = (const float*)d_in[11];

    const int nb = in_sizes[1] / 2;

    hipLaunchKernelGGL(transpose_w, dim3(13), dim3(256), 0, stream, W1, W2, Wb, d_ws);

    const __half* h1 = (const __half*)d_ws;
    const __half* h2 = h1 + 2560;
    const float*  wb = (const float*)(h1 + 5120);

    const int nblk = (nb + BPB - 1) / BPB;
    hipLaunchKernelGGL(bctmd_kernel, dim3(nblk), dim3(256), 0, stream,
                       A, nbr, disp, b1, gamma, beta, b2, bb, Wtp,
                       h1, h2, wb, (float*)d_out, nb);
}

// Round 20
// 176.604 us; speedup vs baseline: 1.1257x; 1.0535x over previous
//
#include <hip/hip_runtime.h>
#include <hip/hip_fp16.h>

#define NF   16
#define NLM  25      // (L_OUT+1)^2
#define BPB  16      // bonds per block
#define YSTR 816     // halves per bond in LDS: 800 + 16 pad; 1632 B stride

typedef _Float16 h2f __attribute__((ext_vector_type(2)));

#if defined(__has_builtin)
#if __has_builtin(__builtin_amdgcn_fdot2)
#define FDOT2(a,b,c) __builtin_amdgcn_fdot2((a),(b),(c),false)
#endif
#endif
#ifndef FDOT2
#define FDOT2(a,b,c) ((c) + (float)(a)[0]*(float)(b)[0] + (float)(a)[1]*(float)(b)[1])
#endif

// Wave-private LDS fence (R16): LDS rows are only shared within one wave,
// HW LDS is in-order per wave, so a compiler-reorder fence replaces s_barrier.
#define WAVE_LDS_FENCE() asm volatile("" ::: "memory")

// Non-temporal store for the streamed, write-once output (R17: -5us).
#define NT_STORE(p, v) __builtin_nontemporal_store((v), (p))

// ======================= compile-time real Clebsch-Gordan =======================
constexpr double FT[12] = {1.,1.,2.,6.,24.,120.,720.,5040.,40320.,362880.,3628800.,39916800.};

constexpr double csqrt(double x){
    if (x <= 0.0) return 0.0;
    double g = x > 1.0 ? x : 1.0;
    for (int i = 0; i < 60; ++i){ double n = 0.5*(g + x/g); if (n == g) break; g = n; }
    return g;
}

constexpr double cgc(int j1,int m1,int j2,int m2,int j3,int m3){
    if (m1 + m2 != m3) return 0.0;
    int dj = j1 > j2 ? j1 - j2 : j2 - j1;
    if (j3 < dj || j3 > j1 + j2) return 0.0;
    if (m1 < -j1 || m1 > j1 || m2 < -j2 || m2 > j2 || m3 < -j3 || m3 > j3) return 0.0;
    double X = (2*j3+1)*FT[j1+j2-j3]*FT[j1-j2+j3]*FT[-j1+j2+j3]/FT[j1+j2+j3+1];
    double Y = FT[j1+m1]*FT[j1-m1]*FT[j2+m2]*FT[j2-m2]*FT[j3+m3]*FT[j3-m3];
    double pre = csqrt(X*Y);
    double s = 0.0;
    int kmin = 0; if (j2-j3-m1 > kmin) kmin = j2-j3-m1; if (j1-j3+m2 > kmin) kmin = j1-j3+m2;
    int kmax = j1+j2-j3; if (j1-m1 < kmax) kmax = j1-m1; if (j2+m2 < kmax) kmax = j2+m2;
    for (int k = kmin; k <= kmax; ++k)
        s += ((k & 1) ? -1.0 : 1.0) /
             (FT[k]*FT[j1+j2-j3-k]*FT[j1-m1-k]*FT[j2+m2-k]*FT[j3-j2+m1+k]*FT[j3-j1-m2+k]);
    return pre*s;
}

struct cplx { double re, im; };

constexpr cplx Uent(int l, int a, int col){
    int mp = a - l, mm = col - l;
    const double s2 = 0.70710678118654752440;
    if (mp == 0) return (mm == 0) ? cplx{1.0,0.0} : cplx{0.0,0.0};
    if (mp > 0){
        double sgn = (mp & 1) ? -1.0 : 1.0;
        if (mm ==  mp) return cplx{sgn*s2, 0.0};
        if (mm == -mp) return cplx{s2, 0.0};
        return cplx{0.0,0.0};
    }
    int q = -mp; double sgn = (q & 1) ? -1.0 : 1.0;
    if (mm ==  q) return cplx{0.0, -sgn*s2};
    if (mm == -q) return cplx{0.0,  s2};
    return cplx{0.0,0.0};
}

constexpr double realcg(int l1,int l2,int l3,int a,int b,int c){
    double re = 0.0, im = 0.0;
    for (int m = -l1; m <= l1; ++m){
        cplx u1 = Uent(l1, a, l1+m); u1.im = -u1.im;          // conj
        if (u1.re == 0.0 && u1.im == 0.0) continue;
        for (int n = -l2; n <= l2; ++n){
            cplx u2 = Uent(l2, b, l2+n); u2.im = -u2.im;      // conj
            if (u2.re == 0.0 && u2.im == 0.0) continue;
            int k = m + n; if (k < -l3 || k > l3) continue;
            cplx u3 = Uent(l3, c, l3+k);
            if (u3.re == 0.0 && u3.im == 0.0) continue;
            double g = cgc(l1, m, l2, n, l3, k);
            if (g == 0.0) continue;
            double pr = u1.re*u2.re - u1.im*u2.im;
            double pi = u1.re*u2.im + u1.im*u2.re;
            re += (pr*u3.re - pi*u3.im)*g;
            im += (pr*u3.im + pi*u3.re)*g;
        }
    }
    double o = re + im;
    if (o < 1e-12 && o > -1e-12) o = 0.0;
    return o;
}

template<int L1,int L2,int L3> struct CGT { float v[2*L1+1][2*L2+1][2*L3+1]; };

template<int L1,int L2,int L3>
constexpr CGT<L1,L2,L3> makeCG(){
    CGT<L1,L2,L3> t{};
    for (int a = 0; a < 2*L1+1; ++a)
        for (int b = 0; b < 2*L2+1; ++b)
            for (int c = 0; c < 2*L3+1; ++c)
                t.v[a][b][c] = (float)realcg(L1, L2, L3, a, b, c);
    return t;
}

// ======================= tensor-product path (fully unrolled, sparse) =======================
template<int L1,int L2,int L3,int PIDX>
__device__ __forceinline__ void tp_path(const float (&bed)[9], const float (&y)[2][NLM],
                                        float (&o)[2][NLM], const float* __restrict__ Wtp, int g){
    static constexpr CGT<L1,L2,L3> C = makeCG<L1,L2,L3>();
    constexpr int K = 2*L3+1;
    float a0[K], a1[K];
    #pragma unroll
    for (int k = 0; k < K; ++k){ a0[k] = 0.f; a1[k] = 0.f; }
    #pragma unroll
    for (int n = 0; n < 2*L1+1; ++n){
        const float bn = bed[L1*L1 + n];
        #pragma unroll
        for (int m = 0; m < 2*L2+1; ++m){
            const float p0 = bn * y[0][L2*L2 + m];
            const float p1 = bn * y[1][L2*L2 + m];
            #pragma unroll
            for (int k = 0; k < K; ++k){
                const float c = C.v[n][m][k];
                if (c != 0.f){        // folds at compile time -> sparse code
                    a0[k] = fmaf(c, p0, a0[k]);
                    a1[k] = fmaf(c, p1, a1[k]);
                }
            }
        }
    }
    const float w0 = Wtp[(PIDX*2 + 0)*NF + g];
    const float w1 = Wtp[(PIDX*2 + 1)*NF + g];
    #pragma unroll
    for (int k = 0; k < K; ++k){
        if (L1 & 1){   // odd l1: parity channels swap
            o[0][L3*L3 + k] = fmaf(w1, a1[k], o[0][L3*L3 + k]);
            o[1][L3*L3 + k] = fmaf(w0, a0[k], o[1][L3*L3 + k]);
        } else {
            o[0][L3*L3 + k] = fmaf(w0, a0[k], o[0][L3*L3 + k]);
            o[1][L3*L3 + k] = fmaf(w1, a1[k], o[1][L3*L3 + k]);
        }
    }
}

// ======================= setup kernels =======================
// ws layout (bytes): Wt1h f16 @0 (5120), Wt2h f16 @5120 (5120), Wtb f32 @10240
// (3072), A16 f16 table @16384 (in_sizes[0]*2 bytes = 16 MB).
__global__ void transpose_w(const float* __restrict__ W1, const float* __restrict__ W2,
                            const float* __restrict__ Wb, void* __restrict__ wsv){
    __half* h1 = (__half*)wsv;
    __half* h2 = h1 + 2560;
    float*  wb = (float*)(h1 + 5120);
    int idx = blockIdx.x*256 + threadIdx.x;
    if (idx < 2560){
        int mat = idx >> 8, r = (idx >> 4) & 15, c = idx & 15;
        h1[idx] = __float2half_rn(W1[mat*256 + c*16 + r]);
        h2[idx] = __float2half_rn(W2[mat*256 + c*16 + r]);
    } else if (idx < 3328){
        int k = idx - 2560; int mat = k >> 8, r = (k >> 4) & 15, c = k & 15;
        wb[k] = Wb[mat*256 + c*16 + r];
    }
}

// Convert A (f32) -> A16 (f16) once per launch; halves the gather footprint
// (32->16 MB) so more of it survives L2/L3 against the 250MB output stream.
__global__ void conv_a16(const float4* __restrict__ A4, __half2* __restrict__ A16v, int n4){
    int idx = blockIdx.x*blockDim.x + threadIdx.x;
    for (; idx < n4; idx += gridDim.x*blockDim.x){
        float4 v = A4[idx];
        A16v[2*idx]   = __float22half2_rn(make_float2(v.x, v.y));
        A16v[2*idx+1] = __float22half2_rn(make_float2(v.z, v.w));
    }
}

struct H8 { float4 a, b; };   // 8 half2 = 32 B

// ============ shared post-staging body (identical math to R17/R19) ============
__device__ __forceinline__ void rest_of_kernel(__half* yb, int bond, int g,
        const float* __restrict__ disp, const float* __restrict__ b1,
        const float* __restrict__ gamma, const float* __restrict__ beta,
        const float* __restrict__ b2, const float* __restrict__ bb,
        const float* __restrict__ Wtp, const __half* __restrict__ Wt1h,
        const __half* __restrict__ Wt2h, const float* __restrict__ Wtb,
        float* __restrict__ out, bool act)
{
    float y[2][NLM];
    if (act){
        // ---- edense1 ----
        #pragma unroll
        for (int p = 0; p < 2; ++p){
            #pragma unroll
            for (int l = 0; l < 5; ++l){
                H8 wv = *(const H8*)(Wt1h + (((p*5 + l)*16 + g) << 4));
                const h2f* w = (const h2f*)&wv;
                #pragma unroll
                for (int m = 0; m < 2*l+1; ++m){
                    const int lm = l*l + m;
                    H8 rv = *(const H8*)&yb[p*400 + lm*16];
                    const h2f* v = (const h2f*)&rv;
                    float acc = 0.f;
                    #pragma unroll
                    for (int q = 0; q < 8; ++q) acc = FDOT2(v[q], w[q], acc);
                    y[p][lm] = acc;
                }
            }
        }
        y[0][0] += b1[g];

        // ---- eln ----
        float s0 = y[0][0];
        #pragma unroll
        for (int p = 0; p < 2; ++p){
            #pragma unroll
            for (int l = 0; l < 5; ++l){
                float n2 = 0.f;
                #pragma unroll
                for (int m = 0; m < 2*l+1; ++m){ float v = y[p][l*l+m]; n2 = fmaf(v, v, n2); }
                #pragma unroll
                for (int d = 1; d < 16; d <<= 1) n2 += __shfl_xor(n2, d, 16);
                float rinv = rsqrtf(n2*(1.f/16.f) + 1e-5f);
                float sc = rinv * gamma[(p*5 + l)*16 + g];
                #pragma unroll
                for (int m = 0; m < 2*l+1; ++m) y[p][l*l+m] *= sc;
            }
        }
        float mu = s0, sq = s0*s0;
        #pragma unroll
        for (int d = 1; d < 16; d <<= 1){ mu += __shfl_xor(mu, d, 16); sq += __shfl_xor(sq, d, 16); }
        mu *= (1.f/16.f); sq *= (1.f/16.f);
        float var = sq - mu*mu;
        float sh = (s0 - mu)*rsqrtf(var + 1e-5f)*gamma[g] + beta[g];
        y[0][0] = sh;

        // ---- emish ----
        float s  = sh;
        float es = __expf(fminf(s, 30.f));
        float es2 = es*es;
        float t   = (es2 + 2.f*es) / (es2 + 2.f*es + 2.f);
        float sig = es / (1.f + es);
        float fv  = s*t;
        float fp  = t + s*(1.f - t*t)*sig;
        #pragma unroll
        for (int p = 0; p < 2; ++p)
            #pragma unroll
            for (int lm = 0; lm < NLM; ++lm) y[p][lm] *= fp;
        y[0][0] = fv;
    }
    WAVE_LDS_FENCE();

    if (act){
        #pragma unroll
        for (int p = 0; p < 2; ++p)
            #pragma unroll
            for (int lm = 0; lm < NLM; ++lm)
                yb[p*400 + lm*16 + g] = __float2half_rn(y[p][lm]);
    }
    WAVE_LDS_FENCE();

    if (act){
        // ---- edense2 + b2 + residual ----
        #pragma unroll
        for (int p = 0; p < 2; ++p){
            #pragma unroll
            for (int l = 0; l < 5; ++l){
                H8 wv = *(const H8*)(Wt2h + (((p*5 + l)*16 + g) << 4));
                const h2f* w = (const h2f*)&wv;
                #pragma unroll
                for (int m = 0; m < 2*l+1; ++m){
                    const int lm = l*l + m;
                    H8 rv = *(const H8*)&yb[p*400 + lm*16];
                    const h2f* v = (const h2f*)&rv;
                    float acc = 0.f;
                    #pragma unroll
                    for (int q = 0; q < 8; ++q) acc = FDOT2(v[q], w[q], acc);
                    y[p][lm] += acc;
                }
            }
        }
        y[0][0] += b2[g];

        // ---- basis + basis edense (rank-1 factorized) ----
        float dx = disp[3*bond], dy = disp[3*bond+1], dz = disp[3*bond+2];
        float r  = sqrtf(dx*dx + dy*dy + dz*dz);
        float ir = 1.f/(r + 1e-12f);
        float ux = dx*ir, uy = dy*ir, uz = dz*ir;
        float Y[9];
        Y[0] = 0.28209479177387814f;
        Y[1] = 0.4886025119029199f*uy; Y[2] = 0.4886025119029199f*uz; Y[3] = 0.4886025119029199f*ux;
        Y[4] = 1.0925484305920792f*ux*uy; Y[5] = 1.0925484305920792f*uy*uz;
        Y[6] = 0.31539156525252005f*(3.f*uz*uz - 1.f);
        Y[7] = 1.0925484305920792f*ux*uz; Y[8] = 0.5462742152960396f*(ux*ux - uy*uy);
        float cut = (r < 5.0f) ? 0.5f*(__cosf(r*0.62831853071795864769f) + 1.f) : 0.f;
        float rb[16];
        #pragma unroll
        for (int f = 0; f < 16; ++f){
            float d = (r - (float)f*(1.f/3.f))*3.2f;
            rb[f] = __expf(-d*d)*cut;
        }
        float t3[3];
        #pragma unroll
        for (int l = 0; l < 3; ++l){
            const float4* wp = (const float4*)(Wtb + (l*16 + g)*16);
            float acc = 0.f;
            #pragma unroll
            for (int q = 0; q < 4; ++q){
                float4 t = wp[q];
                acc = fmaf(rb[4*q],   t.x, acc);
                acc = fmaf(rb[4*q+1], t.y, acc);
                acc = fmaf(rb[4*q+2], t.z, acc);
                acc = fmaf(rb[4*q+3], t.w, acc);
            }
            t3[l] = acc;
        }
        float bed[9];
        bed[0] = Y[0]*t3[0] + bb[g];
        #pragma unroll
        for (int m = 1; m < 4; ++m) bed[m] = Y[m]*t3[1];
        #pragma unroll
        for (int m = 4; m < 9; ++m) bed[m] = Y[m]*t3[2];

        // ---- tensor product (33 paths) ----
        float o[2][NLM];
        #pragma unroll
        for (int p = 0; p < 2; ++p)
            #pragma unroll
            for (int lm = 0; lm < NLM; ++lm) o[p][lm] = 0.f;

        tp_path<0,0,0, 0>(bed, y, o, Wtp, g);
        tp_path<0,1,1, 1>(bed, y, o, Wtp, g);
        tp_path<0,2,2, 2>(bed, y, o, Wtp, g);
        tp_path<0,3,3, 3>(bed, y, o, Wtp, g);
        tp_path<0,4,4, 4>(bed, y, o, Wtp, g);
        tp_path<1,0,1, 5>(bed, y, o, Wtp, g);
        tp_path<1,1,0, 6>(bed, y, o, Wtp, g);
        tp_path<1,1,1, 7>(bed, y, o, Wtp, g);
        tp_path<1,1,2, 8>(bed, y, o, Wtp, g);
        tp_path<1,2,1, 9>(bed, y, o, Wtp, g);
        tp_path<1,2,2,10>(bed, y, o, Wtp, g);
        tp_path<1,2,3,11>(bed, y, o, Wtp, g);
        tp_path<1,3,2,12>(bed, y, o, Wtp, g);
        tp_path<1,3,3,13>(bed, y, o, Wtp, g);
        tp_path<1,3,4,14>(bed, y, o, Wtp, g);
        tp_path<1,4,3,15>(bed, y, o, Wtp, g);
        tp_path<1,4,4,16>(bed, y, o, Wtp, g);
        tp_path<2,0,2,17>(bed, y, o, Wtp, g);
        tp_path<2,1,1,18>(bed, y, o, Wtp, g);
        tp_path<2,1,2,19>(bed, y, o, Wtp, g);
        tp_path<2,1,3,20>(bed, y, o, Wtp, g);
        tp_path<2,2,0,21>(bed, y, o, Wtp, g);
        tp_path<2,2,1,22>(bed, y, o, Wtp, g);
        tp_path<2,2,2,23>(bed, y, o, Wtp, g);
        tp_path<2,2,3,24>(bed, y, o, Wtp, g);
        tp_path<2,2,4,25>(bed, y, o, Wtp, g);
        tp_path<2,3,1,26>(bed, y, o, Wtp, g);
        tp_path<2,3,2,27>(bed, y, o, Wtp, g);
        tp_path<2,3,3,28>(bed, y, o, Wtp, g);
        tp_path<2,3,4,29>(bed, y, o, Wtp, g);
        tp_path<2,4,2,30>(bed, y, o, Wtp, g);
        tp_path<2,4,3,31>(bed, y, o, Wtp, g);
        tp_path<2,4,4,32>(bed, y, o, Wtp, g);

        float* op = out + (size_t)bond*800;
        #pragma unroll
        for (int p = 0; p < 2; ++p)
            #pragma unroll
            for (int lm = 0; lm < NLM; ++lm)
                NT_STORE(&op[p*400 + lm*16 + g], o[p][lm]);
    }
}

// ======================= main kernel, f16-A gather (R20) =======================
__global__ __launch_bounds__(256, 3)
void bctmd_kernel16(const __half* __restrict__ A16, const int* __restrict__ nbr,
                    const float* __restrict__ disp,
                    const float* __restrict__ b1, const float* __restrict__ gamma,
                    const float* __restrict__ beta, const float* __restrict__ b2,
                    const float* __restrict__ bb, const float* __restrict__ Wtp,
                    const __half* __restrict__ Wt1h, const __half* __restrict__ Wt2h,
                    const float* __restrict__ Wtb,
                    float* __restrict__ out, int nb)
{
    __shared__ __align__(16) __half ybuf[BPB*YSTR];
    const int tid  = threadIdx.x;
    const int bl   = tid >> 4;
    const int g    = tid & 15;
    const int bond = blockIdx.x*BPB + bl;
    const bool act = bond < nb;
    __half* yb = &ybuf[bl*YSTR];

    // ---- stage A: y0 = A16[i] + A16[j] -> LDS (f16, half the gather bytes) ----
    if (act){
        const int i = nbr[2*bond], j = nbr[2*bond+1];
        const uint4* Ai = (const uint4*)(A16 + (size_t)i*800);
        const uint4* Aj = (const uint4*)(A16 + (size_t)j*800);
        #pragma unroll
        for (int it = 0; it < 7; ++it){
            int q = g + 16*it;
            if (q < 100){
                uint4 a = Ai[q], b = Aj[q];
                const __half2* ha = (const __half2*)&a;
                const __half2* hb = (const __half2*)&b;
                __half2* d = (__half2*)&yb[8*q];
                d[0] = __hadd2(ha[0], hb[0]);
                d[1] = __hadd2(ha[1], hb[1]);
                d[2] = __hadd2(ha[2], hb[2]);
                d[3] = __hadd2(ha[3], hb[3]);
            }
        }
    }
    WAVE_LDS_FENCE();

    rest_of_kernel(yb, bond, g, disp, b1, gamma, beta, b2, bb, Wtp,
                   Wt1h, Wt2h, Wtb, out, act);
}

// ======================= fallback: f32-A gather (exact R19, proven 186us) =======================
__global__ __launch_bounds__(256, 3)
void bctmd_kernel(const float* __restrict__ A, const int* __restrict__ nbr,
                  const float* __restrict__ disp,
                  const float* __restrict__ b1, const float* __restrict__ gamma,
                  const float* __restrict__ beta, const float* __restrict__ b2,
                  const float* __restrict__ bb, const float* __restrict__ Wtp,
                  const __half* __restrict__ Wt1h, const __half* __restrict__ Wt2h,
                  const float* __restrict__ Wtb,
                  float* __restrict__ out, int nb)
{
    __shared__ __align__(16) __half ybuf[BPB*YSTR];
    const int tid  = threadIdx.x;
    const int bl   = tid >> 4;
    const int g    = tid & 15;
    const int bond = blockIdx.x*BPB + bl;
    const bool act = bond < nb;
    __half* yb = &ybuf[bl*YSTR];

    if (act){
        const int i = nbr[2*bond], j = nbr[2*bond+1];
        const float4* Ai = (const float4*)(A + (size_t)i*800);
        const float4* Aj = (const float4*)(A + (size_t)j*800);
        #pragma unroll
        for (int it = 0; it < 13; ++it){
            int q = g + 16*it;
            if (q < 200){
                float4 a = Ai[q], b = Aj[q];
                __half2* d = (__half2*)&yb[4*q];
                d[0] = __float22half2_rn(make_float2(a.x+b.x, a.y+b.y));
                d[1] = __float22half2_rn(make_float2(a.z+b.z, a.w+b.w));
            }
        }
    }
    WAVE_LDS_FENCE();

    rest_of_kernel(yb, bond, g, disp, b1, gamma, beta, b2, bb, Wtp,
                   Wt1h, Wt2h, Wtb, out, act);
}

extern "C" void kernel_launch(void* const* d_in, const int* in_sizes, int n_in,
                              void* d_out, int out_size, void* d_ws, size_t ws_size,
                              hipStream_t stream){
    const float* A     = (const float*)d_in[0];
    const int*   nbr   = (const int*)d_in[1];
    const float* disp  = (const float*)d_in[2];
    const float* W1    = (const float*)d_in[3];
    const float* b1    = (const float*)d_in[4];
    const float* gamma = (const float*)d_in[5];
    const float* beta  = (const float*)d_in[6];
    const float* W2    = (const float*)d_in[7];
    const float* b2    = (const float*)d_in[8];
    const float* Wb    = (const float*)d_in[9];
    const float* bb    = (const float*)d_in[10];
    const float* Wtp   = (const float*)d_in[11];

    const int nb = in_sizes[1] / 2;
    const int nA = in_sizes[0];            // total floats in A (8M)

    hipLaunchKernelGGL(transpose_w, dim3(13), dim3(256), 0, stream, W1, W2, Wb, d_ws);

    const __half* h1 = (const __half*)d_ws;
    const __half* h2 = h1 + 2560;
    const float*  wb = (const float*)(h1 + 5120);

    const int nblk = (nb + BPB - 1) / BPB;
    const size_t a16_off = 16384;                         // bytes
    const size_t a16_bytes = (size_t)nA * sizeof(__half); // 16 MB

    if (ws_size >= a16_off + a16_bytes && (nA & 3) == 0){
        __half* A16 = (__half*)((char*)d_ws + a16_off);
        hipLaunchKernelGGL(conv_a16, dim3(2048), dim3(256), 0, stream,
                           (const float4*)A, (__half2*)A16, nA/4);
        hipLaunchKernelGGL(bctmd_kernel16, dim3(nblk), dim3(256), 0, stream,
                           A16, nbr, disp, b1, gamma, beta, b2, bb, Wtp,
                           h1, h2, wb, (float*)d_out, nb);
    } else {
        hipLaunchKernelGGL(bctmd_kernel, dim3(nblk), dim3(256), 0, stream,
                           A, nbr, disp, b1, gamma, beta, b2, bb, Wtp,
                           h1, h2, wb, (float*)d_out, nb);
    }
}